// Round 4
// baseline (157.512 us; speedup 1.0000x reference)
//
#include <hip/hip_runtime.h>
#include <hip/hip_bf16.h>

// Problem constants
#define BB 512
#define LL 1024
#define AA 13
#define NBP 5
#define NTOT (BB * LL)
#define EPSV 1e-5f

// ws layout (floats)
#define WS_F     192       // 10: F[nn] = sum over half-l of flw
#define WS_PART  256       // 256 blocks * 40 moment partials
#define WS_CONST 10496     // 64 channels * 16 packed consts (written by k_prep)
#define WS_S     16384     // 1024 half-blocks * 640 partial-S floats (2.62 MB)

typedef __attribute__((ext_vector_type(8))) short bhalf8;   // 8 bf16 in 4 VGPRs (MFMA A/B frag)
typedef __attribute__((ext_vector_type(4))) float floatx4;  // MFMA C/D frag

// ---- packed bf16 helpers (compiler emits v_cvt_pk_bf16_f32; do NOT hand-write asm) ----
__device__ __forceinline__ unsigned int pk_bf16(float a, float b) {
    __hip_bfloat162 h = __float22bfloat162_rn(make_float2(a, b));  // low = a, high = b
    union { __hip_bfloat162 h2; unsigned int u; } cv; cv.h2 = h;
    return cv.u;
}

// ---- DPP wave64 sum: result valid in lane 63 (VALU pipe, no LDS) ----
template<int CTRL, int RM, bool BC>
__device__ __forceinline__ float dppadd(float v) {
    int t = __builtin_amdgcn_update_dpp(0, __float_as_int(v), CTRL, RM, 0xf, BC);
    return v + __int_as_float(t);
}
__device__ __forceinline__ float wave_sum(float v) {
    v = dppadd<0x111, 0xf, true >(v);   // row_shr:1
    v = dppadd<0x112, 0xf, true >(v);   // row_shr:2
    v = dppadd<0x114, 0xf, true >(v);   // row_shr:4
    v = dppadd<0x118, 0xf, true >(v);   // row_shr:8
    v = dppadd<0x142, 0xa, false>(v);   // row_bcast15
    v = dppadd<0x143, 0xc, false>(v);   // row_bcast31 -> lane63 total
    return v;
}

// ---------------- Kernel 1: depthwise-output moment partials + flw half-row sums ----------------
__global__ __launch_bounds__(256) void k_moments(
    const float* __restrict__ src,
    const float* __restrict__ dw1,
    const float* __restrict__ dw2,
    const float* __restrict__ flw,
    float* __restrict__ ws)
{
    __shared__ float red[4][40];
    __shared__ float fred[4];
    int tid = threadIdx.x;
    int gid = blockIdx.x * 256 + tid;
    int b = gid >> 7, L0 = (gid & 127) << 3;     // 8-wide strip per thread
    const float* sb = src + b * (5 * LL);

    float w1[5][5], w2[5][3];
#pragma unroll
    for (int c = 0; c < 5; c++) {
#pragma unroll
        for (int t = 0; t < 5; t++) w1[c][t] = dw1[c*5+t];
#pragma unroll
        for (int t = 0; t < 3; t++) w2[c][t] = dw2[c*3+t];
    }

    // x[c5][m] covers l = L0-4 .. L0+11
    float x[5][16];
#pragma unroll
    for (int c5 = 0; c5 < 5; c5++) {
        const float* sp = sb + c5 * LL;
        float4 xa = (L0 >= 4)    ? *(const float4*)(sp + L0 - 4) : make_float4(0,0,0,0);
        float4 xb = *(const float4*)(sp + L0);
        float4 xc = *(const float4*)(sp + L0 + 4);
        float4 xd = (L0 <= 1012) ? *(const float4*)(sp + L0 + 8) : make_float4(0,0,0,0);
        x[c5][0]=xa.x; x[c5][1]=xa.y; x[c5][2]=xa.z; x[c5][3]=xa.w;
        x[c5][4]=xb.x; x[c5][5]=xb.y; x[c5][6]=xb.z; x[c5][7]=xb.w;
        x[c5][8]=xc.x; x[c5][9]=xc.y; x[c5][10]=xc.z; x[c5][11]=xc.w;
        x[c5][12]=xd.x; x[c5][13]=xd.y; x[c5][14]=xd.z; x[c5][15]=xd.w;
    }

    float acc[40];
#pragma unroll
    for (int k = 0; k < 40; k++) acc[k] = 0.f;

#pragma unroll
    for (int k = 0; k < 8; k++) {              // l = L0 + k
        float d1[5], d2[5];
#pragma unroll
        for (int c5 = 0; c5 < 5; c5++) {
            d1[c5] = w1[c5][0]*x[c5][k+2] + w1[c5][1]*x[c5][k+3] + w1[c5][2]*x[c5][k+4]
                   + w1[c5][3]*x[c5][k+5] + w1[c5][4]*x[c5][k+6];
            d2[c5] = w2[c5][0]*x[c5][k+3] + w2[c5][1]*x[c5][k+4] + w2[c5][2]*x[c5][k+5];
        }
#pragma unroll
        for (int j = 0; j < 5; j++) { acc[j] += d1[j]; acc[20+j] += d2[j]; }
#pragma unroll
        for (int j = 0; j < 5; j++)
#pragma unroll
            for (int kk = j; kk < 5; kk++) {
                int idx = j*(11-j)/2 + (kk - j);
                acc[5+idx]  += d1[j]*d1[kk];
                acc[25+idx] += d2[j]*d2[kk];
            }
    }

    int lane = tid & 63, wv = tid >> 6;
#pragma unroll
    for (int k = 0; k < 40; k++) acc[k] = wave_sum(acc[k]);
    if (lane == 63) {
#pragma unroll
        for (int k = 0; k < 40; k++) red[wv][k] = acc[k];
    }
    __syncthreads();
    if (tid < 40) {
        ws[WS_PART + blockIdx.x * 40 + tid] =
            red[0][tid] + red[1][tid] + red[2][tid] + red[3][tid];
    }

    // F[nn] = sum of one flw half-row; blocks 0..9 own one row each
    if (blockIdx.x < 10) {
        int nn = blockIdx.x;
        int n = nn < 5 ? nn : nn - 5;
        int off = nn < 5 ? 0 : LL;
        float4 v = *(const float4*)(flw + n * (2*LL) + off + tid * 4);
        float s = wave_sum(v.x + v.y + v.z + v.w);
        if (lane == 63) fred[wv] = s;
        __syncthreads();
        if (tid == 0) ws[WS_F + nn] = fred[0] + fred[1] + fred[2] + fred[3];
    }
}

// ---------------- Kernel 2: reduce partials + BN finalize -> packed consts in GLOBAL ws ----------------
__global__ __launch_bounds__(320) void k_prep(
    float* __restrict__ ws,
    const float* __restrict__ pw1, const float* __restrict__ pw2,
    const float* __restrict__ g1,  const float* __restrict__ be1,
    const float* __restrict__ g2,  const float* __restrict__ be2,
    const float* __restrict__ r1w, const float* __restrict__ r2w,
    const float* __restrict__ r1b, const float* __restrict__ r2b)
{
    __shared__ float momS[40];
    int tid = threadIdx.x;
    {
        int k = tid >> 3, sub = tid & 7;
        float v = 0.f;
#pragma unroll 8
        for (int t2 = 0; t2 < 32; t2++) v += ws[WS_PART + (sub + (t2 << 3)) * 40 + k];
        v += __shfl_xor(v, 1, 64);
        v += __shfl_xor(v, 2, 64);
        v += __shfl_xor(v, 4, 64);
        if (sub == 0) momS[k] = v;
    }
    __syncthreads();
    if (tid < 64) {
        int brc = tid >> 5, o = tid & 31;
        const float invN = 1.0f / (float)NTOT;
        const float* pw = brc ? pw2 : pw1;
        const float* rw = brc ? r2w : r1w;
        const float* s  = momS + (brc ? 20 : 0);
        const float* M  = momS + (brc ? 25 : 5);
        float pwv[5], rwv[5], md[5];
#pragma unroll
        for (int j = 0; j < 5; j++) { pwv[j] = pw[o*5+j]; rwv[j] = rw[o*5+j]; md[j] = s[j] * invN; }
        float meanY = 0.f;
#pragma unroll
        for (int j = 0; j < 5; j++) meanY += pwv[j] * md[j];
        float ey2 = 0.f;
#pragma unroll
        for (int j = 0; j < 5; j++)
#pragma unroll
            for (int k = 0; k < 5; k++) {
                int lo = j < k ? j : k, hi = j < k ? k : j;
                int idx = lo*(11-lo)/2 + (hi - lo);
                ey2 += pwv[j] * pwv[k] * (M[idx] * invN);
            }
        float varY = ey2 - meanY * meanY;
        if (varY < 0.f) varY = 0.f;
        float gg = brc ? g2[o] : g1[o];
        float bb = brc ? be2[o] : be1[o];
        float rb = brc ? r2b[o] : r1b[o];
        float sc = gg * rsqrtf(varY + EPSV);
        float sh = bb - meanY * sc;
        float* dst = ws + WS_CONST + tid * 16;
        dst[0] = pwv[0]*sc; dst[1] = pwv[1]*sc; dst[2] = pwv[2]*sc; dst[3] = pwv[3]*sc;
        dst[4] = pwv[4]*sc; dst[5] = sh;        dst[6] = rb;        dst[7] = 0.f;
        dst[8] = rwv[0];    dst[9] = rwv[1];    dst[10] = rwv[2];   dst[11] = rwv[3];
        dst[12] = rwv[4];   dst[13] = 0.f;      dst[14] = 0.f;      dst[15] = 0.f;
    }
}

// ---------------- Kernel 3: e-compute (VALU) + S-contraction (MFMA bf16 hi/lo) -> partial S ----------------
// Grid 1024 = 512 batches x 2 L-halves (occupancy was GRID-limited at grid 512: 2 blocks/CU = 50% hard cap).
// 512 threads = 8 waves; wave gu owns 8 channels. Each block covers 512 l (4 chunks of 128),
// writes partial S (64x10) to ws; k_out combines halves + PQ + out.
// bf16 packing via cvt_pk (RNE) instead of mask/shift: ~3 VALU ops/e vs 5.
// __launch_bounds__ 2nd arg = min BLOCKS/CU on this toolchain (round-5 evidence): (512,4) -> 64-VGPR cap.
__global__ __launch_bounds__(512, 4) void k_fused(
    const float* __restrict__ src,
    const float* __restrict__ dw1,
    const float* __restrict__ dw2,
    const float* __restrict__ flw,
    const float* __restrict__ ws_ro,
    float* __restrict__ ws)
{
    __shared__ __align__(16) unsigned int eBuf[8192]; // 32KB: hi plane [0,16K) B, lo plane [16K,32K) B
                                                      // epilogue alias: part = 2048 floats, Sarr @ f4096

    int tid = threadIdx.x, bb = blockIdx.x;
    int b = bb >> 1, h = bb & 1;                      // batch, L-half
    int lane = tid & 63;
    int gu = __builtin_amdgcn_readfirstlane(tid >> 6);  // wave 0..7 (uniform)
    int br = gu >> 2;                                    // 0: branch1 (waves 0-3, ch 0-31), 1: branch2
    int c0 = gu << 3;                                    // first of this wave's 8 channels

    const float* srcB = src + b * (5 * LL);

    // ---- depthwise taps (wave-uniform -> scalar regs) ----
    float wdw[5][5];
    if (br == 0) {
#pragma unroll
        for (int c5 = 0; c5 < 5; c5++)
#pragma unroll
            for (int t = 0; t < 5; t++) wdw[c5][t] = dw1[c5*5+t];
    } else {
#pragma unroll
        for (int c5 = 0; c5 < 5; c5++) {
            wdw[c5][0] = 0.f;
            wdw[c5][1] = dw2[c5*3+0]; wdw[c5][2] = dw2[c5*3+1]; wdw[c5][3] = dw2[c5*3+2];
            wdw[c5][4] = 0.f;
        }
    }
    // wave-uniform pointer to this wave's 8 channels of packed consts -> s_load (SGPRs)
    const float* cb = ws_ro + WS_CONST + (c0 << 4);

    // MFMA task assignment: wave -> (Mtile mt, Kstep-group kgrp)
    int mt   = gu & 3;           // Mtile 0..3 (channels mt*16..mt*16+15)
    int kgrp = gu >> 2;          // Ksteps {kgrp*2, kgrp*2+1} of 4 per chunk
    floatx4 Cacc = {0.f, 0.f, 0.f, 0.f};

    int nB = lane & 15;                  // B-frag column (output nn); >=10 -> zero rows
    int kg = (lane >> 4) << 3;           // k-octet base within a Kstep
    const float* fbase = flw + (nB % 5) * 2048 + (nB / 5) * 1024;

    char* eb = (char*)eBuf;

#pragma unroll 1
    for (int p = 0; p < 4; ++p) {
        // ---- prefetch B (flw) for this wave's 2 Ksteps; latency hides under e-compute ----
        float fv[2][8];
        {
            int gl0 = (h << 9) + (p << 7) + (kgrp << 6) + kg;
            if (nB < 10) {
                float4 a0 = *(const float4*)(fbase + gl0);
                float4 a1 = *(const float4*)(fbase + gl0 + 4);
                float4 b0 = *(const float4*)(fbase + gl0 + 32);
                float4 b1 = *(const float4*)(fbase + gl0 + 36);
                fv[0][0]=a0.x; fv[0][1]=a0.y; fv[0][2]=a0.z; fv[0][3]=a0.w;
                fv[0][4]=a1.x; fv[0][5]=a1.y; fv[0][6]=a1.z; fv[0][7]=a1.w;
                fv[1][0]=b0.x; fv[1][1]=b0.y; fv[1][2]=b0.z; fv[1][3]=b0.w;
                fv[1][4]=b1.x; fv[1][5]=b1.y; fv[1][6]=b1.z; fv[1][7]=b1.w;
            } else {
#pragma unroll
                for (int j = 0; j < 8; j++) { fv[0][j] = 0.f; fv[1][j] = 0.f; }
            }
        }

        // ---- e-compute: this wave's 8 channels at l = h*512 + p*128 + lane*2 .. +1 (src via L1/L2) ----
        int l0 = (h << 9) + (p << 7) + (lane << 1);
        float dv[5][2], sv[5][2];
#pragma unroll
        for (int c5 = 0; c5 < 5; c5++) {
            const float* s5 = srcB + (c5 << 10);
            float2 xa = (l0 >= 2)    ? *(const float2*)(s5 + l0 - 2) : make_float2(0.f, 0.f);
            float2 xb = *(const float2*)(s5 + l0);
            float2 xc = (l0 <= 1020) ? *(const float2*)(s5 + l0 + 2) : make_float2(0.f, 0.f);
            float xx[6] = {xa.x, xa.y, xb.x, xb.y, xc.x, xc.y};   // l0-2 .. l0+3
            sv[c5][0] = xb.x; sv[c5][1] = xb.y;
            if (br == 0) {
#pragma unroll
                for (int q = 0; q < 2; q++)
                    dv[c5][q] = wdw[c5][0]*xx[q] + wdw[c5][1]*xx[q+1] + wdw[c5][2]*xx[q+2]
                              + wdw[c5][3]*xx[q+3] + wdw[c5][4]*xx[q+4];
            } else {
#pragma unroll
                for (int q = 0; q < 2; q++)
                    dv[c5][q] = wdw[c5][1]*xx[q+1] + wdw[c5][2]*xx[q+2] + wdw[c5][3]*xx[q+3];
            }
        }

        // ---- pack both bf16 planes (hi rne + residual lo) and write to LDS ----
        int wcol = lane << 2;   // 2 l * 2B
#pragma unroll
        for (int ci = 0; ci < 8; ci++) {
            const float4 A  = *(const float4*)(cb + ci*16);      // a0..a3 (pw*sc)
            const float4 B2 = *(const float4*)(cb + ci*16 + 4);  // a4, sh, rb
            const float4 R0 = *(const float4*)(cb + ci*16 + 8);  // r0..r3
            const float4 R1 = *(const float4*)(cb + ci*16 + 12); // r4
            float e[2];
#pragma unroll
            for (int q = 0; q < 2; q++) {
                float y = B2.y + A.x*dv[0][q] + A.y*dv[1][q] + A.z*dv[2][q]
                                + A.w*dv[3][q] + B2.x*dv[4][q];
                float r = B2.z + R0.x*sv[0][q] + R0.y*sv[1][q] + R0.z*sv[2][q]
                                + R0.w*sv[3][q] + R1.x*sv[4][q];
                e[q] = fmaxf(y, 0.f) * r;
            }
            unsigned int hp = pk_bf16(e[0], e[1]);
            float hi0 = __uint_as_float(hp << 16);
            float hi1 = __uint_as_float(hp & 0xFFFF0000u);
            unsigned int lp = pk_bf16(e[0] - hi0, e[1] - hi1);
            int c = c0 + ci;
            // row = c (256B), col byte = (within-chunk l)*2, XOR-swizzled by channel
            int off = (c << 8) + (wcol ^ ((c & 7) << 4));
            *(unsigned int*)(eb + off)         = hp;
            *(unsigned int*)(eb + 16384 + off) = lp;
        }
        __syncthreads();

        // ---- MFMA: (Mtile mt) x (Ksteps kgrp*2, kgrp*2+1), 3 hi/lo terms each ----
        {
            int arow = (mt << 4) + (lane & 15);     // channel 0..63
            int swz  = (arow & 7) << 4;
            int rb2  = arow << 8;
            bhalf8 bH[2], bL[2];
#pragma unroll
            for (int kk = 0; kk < 2; kk++) {
                union { unsigned int u[4]; bhalf8 v; } uh, ul;
#pragma unroll
                for (int j = 0; j < 4; j++) {
                    float f0 = fv[kk][2*j], f1 = fv[kk][2*j+1];
                    unsigned int hp = pk_bf16(f0, f1);
                    float hi0 = __uint_as_float(hp << 16);
                    float hi1 = __uint_as_float(hp & 0xFFFF0000u);
                    uh.u[j] = hp;
                    ul.u[j] = pk_bf16(f0 - hi0, f1 - hi1);
                }
                bH[kk] = uh.v; bL[kk] = ul.v;
            }
#pragma unroll
            for (int kk = 0; kk < 2; kk++) {
                int kbyte = (((kgrp << 6) + (kk << 5) + kg) << 1) ^ swz;
                bhalf8 aH = *(const bhalf8*)(eb + rb2 + kbyte);
                bhalf8 aL = *(const bhalf8*)(eb + 16384 + rb2 + kbyte);
                Cacc = __builtin_amdgcn_mfma_f32_16x16x32_bf16(aH, bH[kk], Cacc, 0, 0, 0);
                Cacc = __builtin_amdgcn_mfma_f32_16x16x32_bf16(aH, bL[kk], Cacc, 0, 0, 0);
                Cacc = __builtin_amdgcn_mfma_f32_16x16x32_bf16(aL, bH[kk], Cacc, 0, 0, 0);
            }
        }
        __syncthreads();   // protect eBuf before next chunk's writes
    }

    // ---- cross-wave reduce of C partials (eBuf reused: part = 8 waves x 256 floats) ----
    {
        float* part = (float*)eBuf;
        // C/D layout: col = lane&15 (n), row = (lane>>4)*4 + reg (m within tile)
        int basep = (gu << 8) + ((lane >> 4) << 6) + (lane & 15);
        part[basep]      = Cacc[0];
        part[basep + 16] = Cacc[1];
        part[basep + 32] = Cacc[2];
        part[basep + 48] = Cacc[3];
    }
    __syncthreads();
    // ---- partial S (64 x 10) -> ws ----
    for (int idx = tid; idx < 640; idx += 512) {
        int c = idx / 10, n = idx - c * 10;
        int mt2 = c >> 4, row = c & 15;
        const float* part = (const float*)eBuf;
        int o = (row << 4) + n;
        ws[WS_S + bb * 640 + idx] = part[mt2 * 256 + o] + part[(4 + mt2) * 256 + o];
    }
}

// ---------------- Kernel 4: combine half-S partials + PQ + out ----------------
__global__ __launch_bounds__(256) void k_out(
    const float* __restrict__ ws,
    const float* __restrict__ ll1w,
    const float* __restrict__ ll1b,
    const float* __restrict__ flb,
    float* __restrict__ out)
{
    __shared__ float llT[832];   // ll1w transposed: [c*13 + a]
    __shared__ float S[640];     // S[c][col], col 0..9
    __shared__ float PQ[130];

    int tid = threadIdx.x, b = blockIdx.x;
    for (int idx = tid; idx < 832; idx += 256) {
        int cc = idx / 13, a = idx - cc * 13;
        llT[idx] = ll1w[a * 64 + cc];
    }
    const float* s0 = ws + WS_S + (b * 2) * 640;
    const float* s1 = ws + WS_S + (b * 2 + 1) * 640;
    for (int idx = tid; idx < 640; idx += 256) S[idx] = s0[idx] + s1[idx];
    __syncthreads();

    // PQ[half][a][n] = sum_c llT[c][a] * S[c][half*5+n] + ll1b[a] * F[half*5+n]
    if (tid < 130) {
        int half = tid >= 65 ? 1 : 0;
        int q = tid - half * 65;
        int a = q / 5, n = q - a * 5;
        int col = half * 5 + n;
        float v = ll1b[a] * ws[WS_F + col];
#pragma unroll 8
        for (int cc = 0; cc < 64; cc++) v += llT[cc * 13 + a] * S[cc * 10 + col];
        PQ[tid] = v;
    }
    __syncthreads();

    // out[b,i,j,n] = P[min,n] + Q[max,n] + flb[n]
    for (int idx = tid; idx < AA * AA * NBP; idx += 256) {
        int i = idx / 65;
        int rr = idx - i * 65;
        int j = rr / 5, n = rr - j * 5;
        int mn = i < j ? i : j, mx = i < j ? j : i;
        out[b * (AA * AA * NBP) + idx] = PQ[mn * 5 + n] + PQ[65 + mx * 5 + n] + flb[n];
    }
}

extern "C" void kernel_launch(void* const* d_in, const int* in_sizes, int n_in,
                              void* d_out, int out_size, void* d_ws, size_t ws_size,
                              hipStream_t stream) {
    const float* src  = (const float*)d_in[0];
    // d_in[1] = mask (unused), d_in[2] = max_atoms (unused, == 13)
    const float* dw1  = (const float*)d_in[3];
    const float* pw1  = (const float*)d_in[4];
    const float* g1   = (const float*)d_in[5];
    const float* be1  = (const float*)d_in[6];
    const float* r1w  = (const float*)d_in[7];
    const float* r1b  = (const float*)d_in[8];
    const float* dw2  = (const float*)d_in[9];
    const float* pw2  = (const float*)d_in[10];
    const float* g2   = (const float*)d_in[11];
    const float* be2  = (const float*)d_in[12];
    const float* r2w  = (const float*)d_in[13];
    const float* r2b  = (const float*)d_in[14];
    const float* ll1w = (const float*)d_in[15];
    const float* ll1b = (const float*)d_in[16];
    const float* flw  = (const float*)d_in[17];
    const float* flb  = (const float*)d_in[18];
    float* ws  = (float*)d_ws;
    float* out = (float*)d_out;

    k_moments<<<256, 256, 0, stream>>>(src, dw1, dw2, flw, ws);
    k_prep<<<1, 320, 0, stream>>>(ws, pw1, pw2, g1, be1, g2, be2, r1w, r2w, r1b, r2b);
    k_fused<<<BB * 2, 512, 0, stream>>>(src, dw1, dw2, flw, ws, ws);
    k_out<<<BB, 256, 0, stream>>>(ws, ll1w, ll1b, flb, out);
}

// Round 5
// 142.095 us; speedup vs baseline: 1.1085x; 1.1085x over previous
//
#include <hip/hip_runtime.h>
#include <hip/hip_bf16.h>

// Problem constants
#define BB 512
#define LL 1024
#define AA 13
#define NBP 5
#define NTOT (BB * LL)
#define EPSV 1e-5f

// ws layout (floats)
#define WS_F     192       // 10: F[nn] = sum over half-l of flw
#define WS_PART  256       // 256 blocks * 40 moment partials
#define WS_CONST 10496     // 64 channels * 16 packed consts (written by k_prep)
#define WS_S     16384     // 1024 half-blocks * 640 partial-S floats (2.62 MB)

typedef __attribute__((ext_vector_type(8))) short bhalf8;   // 8 bf16 in 4 VGPRs (MFMA A/B frag)
typedef __attribute__((ext_vector_type(4))) float floatx4;  // MFMA C/D frag

// ---- packed bf16 helpers (compiler emits v_cvt_pk_bf16_f32; do NOT hand-write asm) ----
__device__ __forceinline__ unsigned int pk_bf16(float a, float b) {
    __hip_bfloat162 h = __float22bfloat162_rn(make_float2(a, b));  // low = a, high = b
    union { __hip_bfloat162 h2; unsigned int u; } cv; cv.h2 = h;
    return cv.u;
}

// ---- DPP wave64 sum: result valid in lane 63 (VALU pipe, no LDS) ----
template<int CTRL, int RM, bool BC>
__device__ __forceinline__ float dppadd(float v) {
    int t = __builtin_amdgcn_update_dpp(0, __float_as_int(v), CTRL, RM, 0xf, BC);
    return v + __int_as_float(t);
}
__device__ __forceinline__ float wave_sum(float v) {
    v = dppadd<0x111, 0xf, true >(v);   // row_shr:1
    v = dppadd<0x112, 0xf, true >(v);   // row_shr:2
    v = dppadd<0x114, 0xf, true >(v);   // row_shr:4
    v = dppadd<0x118, 0xf, true >(v);   // row_shr:8
    v = dppadd<0x142, 0xa, false>(v);   // row_bcast15
    v = dppadd<0x143, 0xc, false>(v);   // row_bcast31 -> lane63 total
    return v;
}

// ---------------- Kernel 1: depthwise-output moment partials + flw half-row sums ----------------
__global__ __launch_bounds__(256) void k_moments(
    const float* __restrict__ src,
    const float* __restrict__ dw1,
    const float* __restrict__ dw2,
    const float* __restrict__ flw,
    float* __restrict__ ws)
{
    __shared__ float red[4][40];
    __shared__ float fred[4];
    int tid = threadIdx.x;
    int gid = blockIdx.x * 256 + tid;
    int b = gid >> 7, L0 = (gid & 127) << 3;     // 8-wide strip per thread
    const float* sb = src + b * (5 * LL);

    float w1[5][5], w2[5][3];
#pragma unroll
    for (int c = 0; c < 5; c++) {
#pragma unroll
        for (int t = 0; t < 5; t++) w1[c][t] = dw1[c*5+t];
#pragma unroll
        for (int t = 0; t < 3; t++) w2[c][t] = dw2[c*3+t];
    }

    // x[c5][m] covers l = L0-4 .. L0+11
    float x[5][16];
#pragma unroll
    for (int c5 = 0; c5 < 5; c5++) {
        const float* sp = sb + c5 * LL;
        float4 xa = (L0 >= 4)    ? *(const float4*)(sp + L0 - 4) : make_float4(0,0,0,0);
        float4 xb = *(const float4*)(sp + L0);
        float4 xc = *(const float4*)(sp + L0 + 4);
        float4 xd = (L0 <= 1012) ? *(const float4*)(sp + L0 + 8) : make_float4(0,0,0,0);
        x[c5][0]=xa.x; x[c5][1]=xa.y; x[c5][2]=xa.z; x[c5][3]=xa.w;
        x[c5][4]=xb.x; x[c5][5]=xb.y; x[c5][6]=xb.z; x[c5][7]=xb.w;
        x[c5][8]=xc.x; x[c5][9]=xc.y; x[c5][10]=xc.z; x[c5][11]=xc.w;
        x[c5][12]=xd.x; x[c5][13]=xd.y; x[c5][14]=xd.z; x[c5][15]=xd.w;
    }

    float acc[40];
#pragma unroll
    for (int k = 0; k < 40; k++) acc[k] = 0.f;

#pragma unroll
    for (int k = 0; k < 8; k++) {              // l = L0 + k
        float d1[5], d2[5];
#pragma unroll
        for (int c5 = 0; c5 < 5; c5++) {
            d1[c5] = w1[c5][0]*x[c5][k+2] + w1[c5][1]*x[c5][k+3] + w1[c5][2]*x[c5][k+4]
                   + w1[c5][3]*x[c5][k+5] + w1[c5][4]*x[c5][k+6];
            d2[c5] = w2[c5][0]*x[c5][k+3] + w2[c5][1]*x[c5][k+4] + w2[c5][2]*x[c5][k+5];
        }
#pragma unroll
        for (int j = 0; j < 5; j++) { acc[j] += d1[j]; acc[20+j] += d2[j]; }
#pragma unroll
        for (int j = 0; j < 5; j++)
#pragma unroll
            for (int kk = j; kk < 5; kk++) {
                int idx = j*(11-j)/2 + (kk - j);
                acc[5+idx]  += d1[j]*d1[kk];
                acc[25+idx] += d2[j]*d2[kk];
            }
    }

    int lane = tid & 63, wv = tid >> 6;
#pragma unroll
    for (int k = 0; k < 40; k++) acc[k] = wave_sum(acc[k]);
    if (lane == 63) {
#pragma unroll
        for (int k = 0; k < 40; k++) red[wv][k] = acc[k];
    }
    __syncthreads();
    if (tid < 40) {
        ws[WS_PART + blockIdx.x * 40 + tid] =
            red[0][tid] + red[1][tid] + red[2][tid] + red[3][tid];
    }

    // F[nn] = sum of one flw half-row; blocks 0..9 own one row each
    if (blockIdx.x < 10) {
        int nn = blockIdx.x;
        int n = nn < 5 ? nn : nn - 5;
        int off = nn < 5 ? 0 : LL;
        float4 v = *(const float4*)(flw + n * (2*LL) + off + tid * 4);
        float s = wave_sum(v.x + v.y + v.z + v.w);
        if (lane == 63) fred[wv] = s;
        __syncthreads();
        if (tid == 0) ws[WS_F + nn] = fred[0] + fred[1] + fred[2] + fred[3];
    }
}

// ---------------- Kernel 2: reduce partials + BN finalize -> packed consts in GLOBAL ws ----------------
__global__ __launch_bounds__(320) void k_prep(
    float* __restrict__ ws,
    const float* __restrict__ pw1, const float* __restrict__ pw2,
    const float* __restrict__ g1,  const float* __restrict__ be1,
    const float* __restrict__ g2,  const float* __restrict__ be2,
    const float* __restrict__ r1w, const float* __restrict__ r2w,
    const float* __restrict__ r1b, const float* __restrict__ r2b)
{
    __shared__ float momS[40];
    int tid = threadIdx.x;
    {
        int k = tid >> 3, sub = tid & 7;
        float v = 0.f;
#pragma unroll 8
        for (int t2 = 0; t2 < 32; t2++) v += ws[WS_PART + (sub + (t2 << 3)) * 40 + k];
        v += __shfl_xor(v, 1, 64);
        v += __shfl_xor(v, 2, 64);
        v += __shfl_xor(v, 4, 64);
        if (sub == 0) momS[k] = v;
    }
    __syncthreads();
    if (tid < 64) {
        int brc = tid >> 5, o = tid & 31;
        const float invN = 1.0f / (float)NTOT;
        const float* pw = brc ? pw2 : pw1;
        const float* rw = brc ? r2w : r1w;
        const float* s  = momS + (brc ? 20 : 0);
        const float* M  = momS + (brc ? 25 : 5);
        float pwv[5], rwv[5], md[5];
#pragma unroll
        for (int j = 0; j < 5; j++) { pwv[j] = pw[o*5+j]; rwv[j] = rw[o*5+j]; md[j] = s[j] * invN; }
        float meanY = 0.f;
#pragma unroll
        for (int j = 0; j < 5; j++) meanY += pwv[j] * md[j];
        float ey2 = 0.f;
#pragma unroll
        for (int j = 0; j < 5; j++)
#pragma unroll
            for (int k = 0; k < 5; k++) {
                int lo = j < k ? j : k, hi = j < k ? k : j;
                int idx = lo*(11-lo)/2 + (hi - lo);
                ey2 += pwv[j] * pwv[k] * (M[idx] * invN);
            }
        float varY = ey2 - meanY * meanY;
        if (varY < 0.f) varY = 0.f;
        float gg = brc ? g2[o] : g1[o];
        float bb = brc ? be2[o] : be1[o];
        float rb = brc ? r2b[o] : r1b[o];
        float sc = gg * rsqrtf(varY + EPSV);
        float sh = bb - meanY * sc;
        float* dst = ws + WS_CONST + tid * 16;
        dst[0] = pwv[0]*sc; dst[1] = pwv[1]*sc; dst[2] = pwv[2]*sc; dst[3] = pwv[3]*sc;
        dst[4] = pwv[4]*sc; dst[5] = sh;        dst[6] = rb;        dst[7] = 0.f;
        dst[8] = rwv[0];    dst[9] = rwv[1];    dst[10] = rwv[2];   dst[11] = rwv[3];
        dst[12] = rwv[4];   dst[13] = 0.f;      dst[14] = 0.f;      dst[15] = 0.f;
    }
}

// ---------------- Kernel 3: barrier-free MFMA K-loop ----------------
// Grid 1024 = 512 batches x 2 L-halves; 512 threads = 8 waves.
// STRUCTURAL CHANGE (r4 post-mortem: throughput invariant to occupancy -> the chunked
// LDS round-trip + 16 barriers/block WAS the limiter):
//  * lane = (one channel row) x (8 consecutive l) == exactly the MFMA A-fragment layout
//    (row=lane&15, k-octet=lane>>4) -> e is born in registers; NO e-LDS-write/read/barrier.
//  * per-l shared data (d1[5], d2[5], sv[5]) staged ONCE (thread t <-> l=t), read-only after
//    one barrier; dv redundancy eliminated.
//  * per-lane channel consts: 13 regs loaded once (no 8-channel const loop).
// LDS 36.9KB; barriers/block: 3. Wave gu: Mtile mt=gu&3 (16 ch), l-quarter lq=gu>>2 (256 l).
__global__ __launch_bounds__(512, 4) void k_fused(
    const float* __restrict__ src,
    const float* __restrict__ dw1,
    const float* __restrict__ dw2,
    const float* __restrict__ flw,
    const float* __restrict__ ws_ro,
    float* __restrict__ ws)
{
    // dAB: entry ((br<<10)+(l<<1)+slot) float4s (32KB), byte-offset XOR ((l>>3)&3)<<4
    //   slot0 = (d0,d1,d2,d3), slot1 = (d4, sv0, sv1, sv2)  [d = d1 for br0, d2 for br1]
    // dC @ float 8192: l -> float2 (sv3, sv4)  (4KB)
    // epilogue alias: part = 2048 floats at offset 0 (after barrier)
    __shared__ __align__(16) float dvS[9216 + 64];

    int tid = threadIdx.x, bb = blockIdx.x;
    int b = bb >> 1, h = bb & 1;                        // batch, L-half
    int lane = tid & 63;
    int gu = __builtin_amdgcn_readfirstlane(tid >> 6);  // wave 0..7 (uniform)
    int mt = gu & 3, lq = gu >> 2;                      // Mtile, l-quarter
    int br = mt >> 1;                                   // 0: branch1 (ch 0-31), 1: branch2

    const float* srcB = src + b * (5 * LL);
    char* base  = (char*)dvS;
    char* cbase = (char*)(dvS + 8192);

    // ---- one-shot staging: thread t computes d1[5], d2[5], sv[5] for l = t ----
    {
        int t = tid, lg = (h << 9) + t;
        int swz = ((t >> 3) & 3) << 4;
        float d1v[5], d2v[5], s0[5];
#pragma unroll
        for (int c5 = 0; c5 < 5; c5++) {
            const float* s5 = srcB + (c5 << 10);
            float xm2 = (lg >= 2)    ? s5[lg - 2] : 0.f;
            float xm1 = (lg >= 1)    ? s5[lg - 1] : 0.f;
            float x0  = s5[lg];
            float xp1 = (lg <= 1022) ? s5[lg + 1] : 0.f;
            float xp2 = (lg <= 1021) ? s5[lg + 2] : 0.f;
            d1v[c5] = dw1[c5*5+0]*xm2 + dw1[c5*5+1]*xm1 + dw1[c5*5+2]*x0
                    + dw1[c5*5+3]*xp1 + dw1[c5*5+4]*xp2;
            d2v[c5] = dw2[c5*3+0]*xm1 + dw2[c5*3+1]*x0 + dw2[c5*3+2]*xp1;
            s0[c5] = x0;
        }
        *(float4*)(base + ((((0<<10)+(t<<1)+0) << 4) ^ swz)) = make_float4(d1v[0],d1v[1],d1v[2],d1v[3]);
        *(float4*)(base + ((((0<<10)+(t<<1)+1) << 4) ^ swz)) = make_float4(d1v[4],s0[0],s0[1],s0[2]);
        *(float4*)(base + ((((1<<10)+(t<<1)+0) << 4) ^ swz)) = make_float4(d2v[0],d2v[1],d2v[2],d2v[3]);
        *(float4*)(base + ((((1<<10)+(t<<1)+1) << 4) ^ swz)) = make_float4(d2v[4],s0[0],s0[1],s0[2]);
        *(float2*)(cbase + (t << 3)) = make_float2(s0[3], s0[4]);
    }
    __syncthreads();

    // ---- per-lane channel consts (13 regs; ch = mt*16 + (lane&15)) ----
    int ch = (mt << 4) + (lane & 15);
    const float* cf = ws_ro + WS_CONST + (ch << 4);
    const float4 A  = *(const float4*)cf;        // a0..a3 (pw*sc)
    const float4 B2 = *(const float4*)(cf + 4);  // a4, sh, rb
    const float4 R0 = *(const float4*)(cf + 8);  // r0..r3
    const float r4w = cf[12];                    // r4

    int nB = lane & 15;                 // B-frag column (nn); >=10 -> zero
    int kg = (lane >> 4) << 3;          // k-octet base
    const float* fbase = flw + (nB % 5) * 2048 + (nB / 5) * 1024;
    floatx4 Cacc = {0.f, 0.f, 0.f, 0.f};

#pragma unroll 1
    for (int s = 0; s < 8; ++s) {
        int lb = (lq << 8) + (s << 5) + kg;     // block-local l base of this lane's octet
        // prefetch B (flw) — latency hides under e-compute
        float4 f0 = make_float4(0,0,0,0), f1 = make_float4(0,0,0,0);
        if (nB < 10) {
            f0 = *(const float4*)(fbase + (h << 9) + lb);
            f1 = *(const float4*)(fbase + (h << 9) + lb + 4);
        }
        // e for this lane's 8 (ch, l) A-frag elements — broadcast LDS reads, no sync
        int sw = ((lb >> 3) & 3) << 4;
        float e[8];
#pragma unroll
        for (int i = 0; i < 8; ++i) {
            int l = lb + i;
            const float4 pa = *(const float4*)(base + ((((br<<10)+(l<<1)+0) << 4) ^ sw));
            const float4 pb = *(const float4*)(base + ((((br<<10)+(l<<1)+1) << 4) ^ sw));
            const float2 pc = *(const float2*)(cbase + (l << 3));
            float y = B2.y + A.x*pa.x + A.y*pa.y + A.z*pa.z + A.w*pa.w + B2.x*pb.x;
            float r = B2.z + R0.x*pb.y + R0.y*pb.z + R0.z*pb.w + R0.w*pc.x + r4w*pc.y;
            e[i] = fmaxf(y, 0.f) * r;
        }
        // pack A frags (hi RNE + residual lo)
        union { unsigned int u[4]; bhalf8 v; } ah, al;
#pragma unroll
        for (int j = 0; j < 4; j++) {
            unsigned int hp = pk_bf16(e[2*j], e[2*j+1]);
            float hi0 = __uint_as_float(hp << 16);
            float hi1 = __uint_as_float(hp & 0xFFFF0000u);
            ah.u[j] = hp;
            al.u[j] = pk_bf16(e[2*j] - hi0, e[2*j+1] - hi1);
        }
        // pack B frags
        float fb[8] = {f0.x, f0.y, f0.z, f0.w, f1.x, f1.y, f1.z, f1.w};
        union { unsigned int u[4]; bhalf8 v; } bh, bl;
#pragma unroll
        for (int j = 0; j < 4; j++) {
            unsigned int hp = pk_bf16(fb[2*j], fb[2*j+1]);
            float hi0 = __uint_as_float(hp << 16);
            float hi1 = __uint_as_float(hp & 0xFFFF0000u);
            bh.u[j] = hp;
            bl.u[j] = pk_bf16(fb[2*j] - hi0, fb[2*j+1] - hi1);
        }
        Cacc = __builtin_amdgcn_mfma_f32_16x16x32_bf16(ah.v, bh.v, Cacc, 0, 0, 0);
        Cacc = __builtin_amdgcn_mfma_f32_16x16x32_bf16(ah.v, bl.v, Cacc, 0, 0, 0);
        Cacc = __builtin_amdgcn_mfma_f32_16x16x32_bf16(al.v, bh.v, Cacc, 0, 0, 0);
    }

    __syncthreads();   // all reads of dvS done; alias as part scratch
    {
        float* part = dvS;
        // C layout: col = lane&15 (nn), row = (lane>>4)*4 + reg (ch within tile)
        int basep = (gu << 8) + ((lane >> 4) << 6) + (lane & 15);
        part[basep]      = Cacc[0];
        part[basep + 16] = Cacc[1];
        part[basep + 32] = Cacc[2];
        part[basep + 48] = Cacc[3];
    }
    __syncthreads();
    // partial S (64 x 10) -> ws; waves (mt, lq=0)=gu mt and (mt, lq=1)=gu 4+mt combine
    for (int idx = tid; idx < 640; idx += 512) {
        int c = idx / 10, n = idx - c * 10;
        int mt2 = c >> 4, m = c & 15;
        const float* part = (const float*)dvS;
        int o = (m << 4) + n;
        ws[WS_S + bb * 640 + idx] = part[mt2 * 256 + o] + part[(4 + mt2) * 256 + o];
    }
}

// ---------------- Kernel 4: combine half-S partials + PQ + out ----------------
__global__ __launch_bounds__(256) void k_out(
    const float* __restrict__ ws,
    const float* __restrict__ ll1w,
    const float* __restrict__ ll1b,
    const float* __restrict__ flb,
    float* __restrict__ out)
{
    __shared__ float llT[832];   // ll1w transposed: [c*13 + a]
    __shared__ float S[640];     // S[c][col], col 0..9
    __shared__ float PQ[130];

    int tid = threadIdx.x, b = blockIdx.x;
    for (int idx = tid; idx < 832; idx += 256) {
        int cc = idx / 13, a = idx - cc * 13;
        llT[idx] = ll1w[a * 64 + cc];
    }
    const float* s0 = ws + WS_S + (b * 2) * 640;
    const float* s1 = ws + WS_S + (b * 2 + 1) * 640;
    for (int idx = tid; idx < 640; idx += 256) S[idx] = s0[idx] + s1[idx];
    __syncthreads();

    // PQ[half][a][n] = sum_c llT[c][a] * S[c][half*5+n] + ll1b[a] * F[half*5+n]
    if (tid < 130) {
        int half = tid >= 65 ? 1 : 0;
        int q = tid - half * 65;
        int a = q / 5, n = q - a * 5;
        int col = half * 5 + n;
        float v = ll1b[a] * ws[WS_F + col];
#pragma unroll 8
        for (int cc = 0; cc < 64; cc++) v += llT[cc * 13 + a] * S[cc * 10 + col];
        PQ[tid] = v;
    }
    __syncthreads();

    // out[b,i,j,n] = P[min,n] + Q[max,n] + flb[n]
    for (int idx = tid; idx < AA * AA * NBP; idx += 256) {
        int i = idx / 65;
        int rr = idx - i * 65;
        int j = rr / 5, n = rr - j * 5;
        int mn = i < j ? i : j, mx = i < j ? j : i;
        out[b * (AA * AA * NBP) + idx] = PQ[mn * 5 + n] + PQ[65 + mx * 5 + n] + flb[n];
    }
}

extern "C" void kernel_launch(void* const* d_in, const int* in_sizes, int n_in,
                              void* d_out, int out_size, void* d_ws, size_t ws_size,
                              hipStream_t stream) {
    const float* src  = (const float*)d_in[0];
    // d_in[1] = mask (unused), d_in[2] = max_atoms (unused, == 13)
    const float* dw1  = (const float*)d_in[3];
    const float* pw1  = (const float*)d_in[4];
    const float* g1   = (const float*)d_in[5];
    const float* be1  = (const float*)d_in[6];
    const float* r1w  = (const float*)d_in[7];
    const float* r1b  = (const float*)d_in[8];
    const float* dw2  = (const float*)d_in[9];
    const float* pw2  = (const float*)d_in[10];
    const float* g2   = (const float*)d_in[11];
    const float* be2  = (const float*)d_in[12];
    const float* r2w  = (const float*)d_in[13];
    const float* r2b  = (const float*)d_in[14];
    const float* ll1w = (const float*)d_in[15];
    const float* ll1b = (const float*)d_in[16];
    const float* flw  = (const float*)d_in[17];
    const float* flb  = (const float*)d_in[18];
    float* ws  = (float*)d_ws;
    float* out = (float*)d_out;

    k_moments<<<256, 256, 0, stream>>>(src, dw1, dw2, flw, ws);
    k_prep<<<1, 320, 0, stream>>>(ws, pw1, pw2, g1, be1, g2, be2, r1w, r2w, r1b, r2b);
    k_fused<<<BB * 2, 512, 0, stream>>>(src, dw1, dw2, flw, ws, ws);
    k_out<<<BB, 256, 0, stream>>>(ws, ll1w, ll1b, flb, out);
}

// Round 6
// 134.117 us; speedup vs baseline: 1.1744x; 1.0595x over previous
//
#include <hip/hip_runtime.h>
#include <hip/hip_bf16.h>

// Problem constants
#define BB 512
#define LL 1024
#define AA 13
#define NBP 5
#define NTOT (BB * LL)
#define EPSV 1e-5f

// ws layout (floats)
#define WS_F     192       // 10: F[nn] = sum over half-l of flw
#define WS_PART  256       // 256 blocks * 40 moment partials
#define WS_CONST 10496     // 64 channels * 16 packed consts (written by k_prep)
#define WS_FLW   16384     // 64KB region: flw bf16 hi plane [0,32K)B, lo plane [32K,64K)B, 16 rows x 1024

typedef __attribute__((ext_vector_type(8))) short bhalf8;   // 8 bf16 in 4 VGPRs (MFMA A/B frag)
typedef __attribute__((ext_vector_type(4))) float floatx4;  // MFMA C/D frag

// ---- truncation hi/lo split, packed 2-at-a-time (r1/r2-proven numerics: absmax 0.0039) ----
// hi = top-16-bit truncation (error captured EXACTLY in residual), lo = trunc(e - hi).
__device__ __forceinline__ void trunc_pair(float e0, float e1, unsigned int& hp, unsigned int& lp) {
    unsigned int u0 = __float_as_uint(e0), u1 = __float_as_uint(e1);
    unsigned int h0 = u0 & 0xFFFF0000u, h1 = u1 & 0xFFFF0000u;
    hp = (h0 >> 16) | h1;
    float l0 = e0 - __uint_as_float(h0);
    float l1 = e1 - __uint_as_float(h1);
    lp = (__float_as_uint(l0) >> 16) | (__float_as_uint(l1) & 0xFFFF0000u);
}

// ---- DPP wave64 sum: result valid in lane 63 (VALU pipe, no LDS) ----
template<int CTRL, int RM, bool BC>
__device__ __forceinline__ float dppadd(float v) {
    int t = __builtin_amdgcn_update_dpp(0, __float_as_int(v), CTRL, RM, 0xf, BC);
    return v + __int_as_float(t);
}
__device__ __forceinline__ float wave_sum(float v) {
    v = dppadd<0x111, 0xf, true >(v);   // row_shr:1
    v = dppadd<0x112, 0xf, true >(v);   // row_shr:2
    v = dppadd<0x114, 0xf, true >(v);   // row_shr:4
    v = dppadd<0x118, 0xf, true >(v);   // row_shr:8
    v = dppadd<0x142, 0xa, false>(v);   // row_bcast15
    v = dppadd<0x143, 0xc, false>(v);   // row_bcast31 -> lane63 total
    return v;
}

// ---------------- Kernel 1: moment partials + flw half-row sums + flw bf16 hi/lo prepack ----------------
__global__ __launch_bounds__(256) void k_moments(
    const float* __restrict__ src,
    const float* __restrict__ dw1,
    const float* __restrict__ dw2,
    const float* __restrict__ flw,
    float* __restrict__ ws)
{
    __shared__ float red[4][40];
    __shared__ float fred[4];
    int tid = threadIdx.x;
    int gid = blockIdx.x * 256 + tid;
    int b = gid >> 7, L0 = (gid & 127) << 3;     // 8-wide strip per thread
    const float* sb = src + b * (5 * LL);

    float w1[5][5], w2[5][3];
#pragma unroll
    for (int c = 0; c < 5; c++) {
#pragma unroll
        for (int t = 0; t < 5; t++) w1[c][t] = dw1[c*5+t];
#pragma unroll
        for (int t = 0; t < 3; t++) w2[c][t] = dw2[c*3+t];
    }

    // x[c5][m] covers l = L0-4 .. L0+11
    float x[5][16];
#pragma unroll
    for (int c5 = 0; c5 < 5; c5++) {
        const float* sp = sb + c5 * LL;
        float4 xa = (L0 >= 4)    ? *(const float4*)(sp + L0 - 4) : make_float4(0,0,0,0);
        float4 xb = *(const float4*)(sp + L0);
        float4 xc = *(const float4*)(sp + L0 + 4);
        float4 xd = (L0 <= 1012) ? *(const float4*)(sp + L0 + 8) : make_float4(0,0,0,0);
        x[c5][0]=xa.x; x[c5][1]=xa.y; x[c5][2]=xa.z; x[c5][3]=xa.w;
        x[c5][4]=xb.x; x[c5][5]=xb.y; x[c5][6]=xb.z; x[c5][7]=xb.w;
        x[c5][8]=xc.x; x[c5][9]=xc.y; x[c5][10]=xc.z; x[c5][11]=xc.w;
        x[c5][12]=xd.x; x[c5][13]=xd.y; x[c5][14]=xd.z; x[c5][15]=xd.w;
    }

    float acc[40];
#pragma unroll
    for (int k = 0; k < 40; k++) acc[k] = 0.f;

#pragma unroll
    for (int k = 0; k < 8; k++) {              // l = L0 + k
        float d1[5], d2[5];
#pragma unroll
        for (int c5 = 0; c5 < 5; c5++) {
            d1[c5] = w1[c5][0]*x[c5][k+2] + w1[c5][1]*x[c5][k+3] + w1[c5][2]*x[c5][k+4]
                   + w1[c5][3]*x[c5][k+5] + w1[c5][4]*x[c5][k+6];
            d2[c5] = w2[c5][0]*x[c5][k+3] + w2[c5][1]*x[c5][k+4] + w2[c5][2]*x[c5][k+5];
        }
#pragma unroll
        for (int j = 0; j < 5; j++) { acc[j] += d1[j]; acc[20+j] += d2[j]; }
#pragma unroll
        for (int j = 0; j < 5; j++)
#pragma unroll
            for (int kk = j; kk < 5; kk++) {
                int idx = j*(11-j)/2 + (kk - j);
                acc[5+idx]  += d1[j]*d1[kk];
                acc[25+idx] += d2[j]*d2[kk];
            }
    }

    int lane = tid & 63, wv = tid >> 6;
#pragma unroll
    for (int k = 0; k < 40; k++) acc[k] = wave_sum(acc[k]);
    if (lane == 63) {
#pragma unroll
        for (int k = 0; k < 40; k++) red[wv][k] = acc[k];
    }
    __syncthreads();
    if (tid < 40) {
        ws[WS_PART + blockIdx.x * 40 + tid] =
            red[0][tid] + red[1][tid] + red[2][tid] + red[3][tid];
    }

    // F[nn] + bf16 hi/lo prepack; blocks 0..9 own one flw half-row each
    if (blockIdx.x < 10) {
        int nn = blockIdx.x;
        int n = nn < 5 ? nn : nn - 5;
        int off = nn < 5 ? 0 : LL;
        float4 v = *(const float4*)(flw + n * (2*LL) + off + tid * 4);
        // prepack: trunc hi/lo planes (consumed by k_fused as raw B-frags)
        {
            unsigned int hp0, lp0, hp1, lp1;
            trunc_pair(v.x, v.y, hp0, lp0);
            trunc_pair(v.z, v.w, hp1, lp1);
            char* fwb = (char*)(ws + WS_FLW);
            *(uint2*)(fwb + nn * 2048 + tid * 8)         = make_uint2(hp0, hp1);
            *(uint2*)(fwb + 32768 + nn * 2048 + tid * 8) = make_uint2(lp0, lp1);
        }
        float s = wave_sum(v.x + v.y + v.z + v.w);
        if (lane == 63) fred[wv] = s;
        __syncthreads();
        if (tid == 0) ws[WS_F + nn] = fred[0] + fred[1] + fred[2] + fred[3];
    } else if (blockIdx.x < 16) {
        // zero pad rows 10..15 (B columns 10-15 then contribute exact zeros)
        int nn = blockIdx.x;
        char* fwb = (char*)(ws + WS_FLW);
        *(uint2*)(fwb + nn * 2048 + tid * 8)         = make_uint2(0u, 0u);
        *(uint2*)(fwb + 32768 + nn * 2048 + tid * 8) = make_uint2(0u, 0u);
    }
}

// ---------------- Kernel 2: reduce partials + BN finalize -> packed consts in GLOBAL ws ----------------
__global__ __launch_bounds__(320) void k_prep(
    float* __restrict__ ws,
    const float* __restrict__ pw1, const float* __restrict__ pw2,
    const float* __restrict__ g1,  const float* __restrict__ be1,
    const float* __restrict__ g2,  const float* __restrict__ be2,
    const float* __restrict__ r1w, const float* __restrict__ r2w,
    const float* __restrict__ r1b, const float* __restrict__ r2b)
{
    __shared__ float momS[40];
    int tid = threadIdx.x;
    {
        int k = tid >> 3, sub = tid & 7;
        float v = 0.f;
#pragma unroll 8
        for (int t2 = 0; t2 < 32; t2++) v += ws[WS_PART + (sub + (t2 << 3)) * 40 + k];
        v += __shfl_xor(v, 1, 64);
        v += __shfl_xor(v, 2, 64);
        v += __shfl_xor(v, 4, 64);
        if (sub == 0) momS[k] = v;
    }
    __syncthreads();
    if (tid < 64) {
        int brc = tid >> 5, o = tid & 31;
        const float invN = 1.0f / (float)NTOT;
        const float* pw = brc ? pw2 : pw1;
        const float* rw = brc ? r2w : r1w;
        const float* s  = momS + (brc ? 20 : 0);
        const float* M  = momS + (brc ? 25 : 5);
        float pwv[5], rwv[5], md[5];
#pragma unroll
        for (int j = 0; j < 5; j++) { pwv[j] = pw[o*5+j]; rwv[j] = rw[o*5+j]; md[j] = s[j] * invN; }
        float meanY = 0.f;
#pragma unroll
        for (int j = 0; j < 5; j++) meanY += pwv[j] * md[j];
        float ey2 = 0.f;
#pragma unroll
        for (int j = 0; j < 5; j++)
#pragma unroll
            for (int k = 0; k < 5; k++) {
                int lo = j < k ? j : k, hi = j < k ? k : j;
                int idx = lo*(11-lo)/2 + (hi - lo);
                ey2 += pwv[j] * pwv[k] * (M[idx] * invN);
            }
        float varY = ey2 - meanY * meanY;
        if (varY < 0.f) varY = 0.f;
        float gg = brc ? g2[o] : g1[o];
        float bb = brc ? be2[o] : be1[o];
        float rb = brc ? r2b[o] : r1b[o];
        float sc = gg * rsqrtf(varY + EPSV);
        float sh = bb - meanY * sc;
        float* dst = ws + WS_CONST + tid * 16;
        dst[0] = pwv[0]*sc; dst[1] = pwv[1]*sc; dst[2] = pwv[2]*sc; dst[3] = pwv[3]*sc;
        dst[4] = pwv[4]*sc; dst[5] = sh;        dst[6] = rb;        dst[7] = 0.f;
        dst[8] = rwv[0];    dst[9] = rwv[1];    dst[10] = rwv[2];   dst[11] = rwv[3];
        dst[12] = rwv[4];   dst[13] = 0.f;      dst[14] = 0.f;      dst[15] = 0.f;
    }
}

// ---------------- Kernel 3: barrier-free MFMA K-loop, full L, in-kernel epilogue ----------------
// Grid 512 (one block per batch), 512 threads = 8 waves. r5 structure kept; changes:
//  * A-pack: truncation hi/lo (r1/r2-proven absmax) instead of software-RNE (codegen bloat).
//  * B-frags: raw uint4 loads from k_moments' prepacked bf16 planes (B-pack VALU eliminated).
//  * full L per block + r3 epilogue (part -> S -> PQ -> out): k_out launch eliminated.
// LDS ~78KB -> 2 blocks/CU (= what grid supplies; occupancy proven non-binding in r4).
// __launch_bounds__ 2nd arg = min BLOCKS/CU on this toolchain: (512,2) -> 128-VGPR cap (proven fit).
__global__ __launch_bounds__(512, 2) void k_fused(
    const float* __restrict__ src,
    const float* __restrict__ dw1,
    const float* __restrict__ dw2,
    const float* __restrict__ ll1w,
    const float* __restrict__ ll1b,
    const float* __restrict__ flb,
    const float* __restrict__ ws_ro,
    float* __restrict__ out)
{
    // base: entry ((br<<11)+(l<<1)+slot) float4s (64KB), byte XOR ((l>>3)&3)<<4
    //   slot0 = (d0,d1,d2,d3), slot1 = (d4, sv0, sv1, sv2)
    // cbase @ float 16384: l -> float2 (sv3, sv4) (8KB)
    // epilogue alias: part = floats [0,2048), Sarr = floats [4096,5120)
    __shared__ __align__(16) float dvS[18432];
    __shared__ float llT[832];   // ll1w transposed: [c*13 + a]
    __shared__ float PQ[130];

    int tid = threadIdx.x, b = blockIdx.x;
    int lane = tid & 63;
    int gu = __builtin_amdgcn_readfirstlane(tid >> 6);  // wave 0..7 (uniform)
    int mt = gu & 3, lq = gu >> 2;                      // Mtile, l-half
    int br = mt >> 1;                                   // 0: branch1 (ch 0-31), 1: branch2

    const float* srcB = src + b * (5 * LL);
    char* base  = (char*)dvS;
    char* cbase = (char*)(dvS + 16384);

    // ---- one-shot staging: thread t computes d1[5], d2[5], sv[5] for l = t, t+512 ----
    for (int t = tid; t < 1024; t += 512) {
        int swz = ((t >> 3) & 3) << 4;
        float d1v[5], d2v[5], s0[5];
#pragma unroll
        for (int c5 = 0; c5 < 5; c5++) {
            const float* s5 = srcB + (c5 << 10);
            float xm2 = (t >= 2)    ? s5[t - 2] : 0.f;
            float xm1 = (t >= 1)    ? s5[t - 1] : 0.f;
            float x0  = s5[t];
            float xp1 = (t <= 1022) ? s5[t + 1] : 0.f;
            float xp2 = (t <= 1021) ? s5[t + 2] : 0.f;
            d1v[c5] = dw1[c5*5+0]*xm2 + dw1[c5*5+1]*xm1 + dw1[c5*5+2]*x0
                    + dw1[c5*5+3]*xp1 + dw1[c5*5+4]*xp2;
            d2v[c5] = dw2[c5*3+0]*xm1 + dw2[c5*3+1]*x0 + dw2[c5*3+2]*xp1;
            s0[c5] = x0;
        }
        *(float4*)(base + ((((0<<11)+(t<<1)+0) << 4) ^ swz)) = make_float4(d1v[0],d1v[1],d1v[2],d1v[3]);
        *(float4*)(base + ((((0<<11)+(t<<1)+1) << 4) ^ swz)) = make_float4(d1v[4],s0[0],s0[1],s0[2]);
        *(float4*)(base + ((((1<<11)+(t<<1)+0) << 4) ^ swz)) = make_float4(d2v[0],d2v[1],d2v[2],d2v[3]);
        *(float4*)(base + ((((1<<11)+(t<<1)+1) << 4) ^ swz)) = make_float4(d2v[4],s0[0],s0[1],s0[2]);
        *(float2*)(cbase + (t << 3)) = make_float2(s0[3], s0[4]);
    }
    // ---- stage ll1w transposed (epilogue-only; K-loop barriers cover it) ----
    for (int idx = tid; idx < 832; idx += 512) {
        int cc = idx / 13, a = idx - cc * 13;
        llT[idx] = ll1w[a * 64 + cc];
    }
    __syncthreads();

    // ---- per-lane channel consts (13 regs; ch = mt*16 + (lane&15)) ----
    int ch = (mt << 4) + (lane & 15);
    const float* cf = ws_ro + WS_CONST + (ch << 4);
    const float4 A  = *(const float4*)cf;        // a0..a3 (pw*sc)
    const float4 B2 = *(const float4*)(cf + 4);  // a4, sh, rb
    const float4 R0 = *(const float4*)(cf + 8);  // r0..r3
    const float r4w = cf[12];                    // r4

    int nB = lane & 15;                 // B-frag column (nn); rows 10-15 are zeros
    int kg = (lane >> 4) << 3;          // k-octet base
    const char* fwb = (const char*)(ws_ro + WS_FLW);
    floatx4 Cacc = {0.f, 0.f, 0.f, 0.f};

#pragma unroll 1
    for (int s = 0; s < 16; ++s) {
        int lb = (lq << 9) + (s << 5) + kg;     // global l base of this lane's octet
        // B frags: raw prepacked loads (no VALU pack, no divergence)
        union { uint4 u; bhalf8 v; } bh, bl;
        bh.u = *(const uint4*)(fwb + (((nB << 10) + lb) << 1));
        bl.u = *(const uint4*)(fwb + 32768 + (((nB << 10) + lb) << 1));
        // e for this lane's 8 (ch, l) A-frag elements — broadcast LDS reads, no sync
        int sw = ((lb >> 3) & 3) << 4;
        float e[8];
#pragma unroll
        for (int i = 0; i < 8; ++i) {
            int l = lb + i;
            const float4 pa = *(const float4*)(base + ((((br<<11)+(l<<1)+0) << 4) ^ sw));
            const float4 pb = *(const float4*)(base + ((((br<<11)+(l<<1)+1) << 4) ^ sw));
            const float2 pc = *(const float2*)(cbase + (l << 3));
            float y = B2.y + A.x*pa.x + A.y*pa.y + A.z*pa.z + A.w*pa.w + B2.x*pb.x;
            float r = B2.z + R0.x*pb.y + R0.y*pb.z + R0.z*pb.w + R0.w*pc.x + r4w*pc.y;
            e[i] = fmaxf(y, 0.f) * r;
        }
        // A-pack: truncation hi/lo (cheap, exact-residual)
        union { unsigned int u[4]; bhalf8 v; } ah, al;
#pragma unroll
        for (int j = 0; j < 4; j++) trunc_pair(e[2*j], e[2*j+1], ah.u[j], al.u[j]);
        Cacc = __builtin_amdgcn_mfma_f32_16x16x32_bf16(ah.v, bh.v, Cacc, 0, 0, 0);
        Cacc = __builtin_amdgcn_mfma_f32_16x16x32_bf16(ah.v, bl.v, Cacc, 0, 0, 0);
        Cacc = __builtin_amdgcn_mfma_f32_16x16x32_bf16(al.v, bh.v, Cacc, 0, 0, 0);
    }

    // ---- cross-wave reduce of C partials (dvS aliased as part scratch) ----
    __syncthreads();
    {
        float* part = dvS;
        // C layout: col = lane&15 (nn), row = (lane>>4)*4 + reg (ch within tile)
        int basep = (gu << 8) + ((lane >> 4) << 6) + (lane & 15);
        part[basep]      = Cacc[0];
        part[basep + 16] = Cacc[1];
        part[basep + 32] = Cacc[2];
        part[basep + 48] = Cacc[3];
    }
    __syncthreads();
    float* SarrF = dvS + 4096;     // S[c][n], 64 x 16 (no overlap with part)
    for (int idx = tid; idx < 1024; idx += 512) {
        int c = idx >> 4, n = idx & 15;
        int mt2 = c >> 4, m = c & 15;
        const float* part = (const float*)dvS;
        int o = (m << 4) + n;
        SarrF[idx] = part[mt2 * 256 + o] + part[(4 + mt2) * 256 + o];
    }
    __syncthreads();

    // ---- PQ[half][a][n] = sum_c llT[c][a] * S[c][half*5+n] + ll1b[a] * F[half*5+n] ----
    if (tid < 130) {
        int half = tid >= 65 ? 1 : 0;
        int q = tid - half * 65;
        int a = q / 5, n = q - a * 5;
        int col = half * 5 + n;
        float v = ll1b[a] * ws_ro[WS_F + col];
#pragma unroll 8
        for (int cc = 0; cc < 64; cc++) v += llT[cc * 13 + a] * SarrF[(cc << 4) + col];
        PQ[tid] = v;
    }
    __syncthreads();

    // ---- out[b,i,j,n] = P[min,n] + Q[max,n] + flb[n] ----
    for (int idx = tid; idx < AA * AA * NBP; idx += 512) {
        int i = idx / 65;
        int rr = idx - i * 65;
        int j = rr / 5, n = rr - j * 5;
        int mn = i < j ? i : j, mx = i < j ? j : i;
        out[b * (AA * AA * NBP) + idx] = PQ[mn * 5 + n] + PQ[65 + mx * 5 + n] + flb[n];
    }
}

extern "C" void kernel_launch(void* const* d_in, const int* in_sizes, int n_in,
                              void* d_out, int out_size, void* d_ws, size_t ws_size,
                              hipStream_t stream) {
    const float* src  = (const float*)d_in[0];
    // d_in[1] = mask (unused), d_in[2] = max_atoms (unused, == 13)
    const float* dw1  = (const float*)d_in[3];
    const float* pw1  = (const float*)d_in[4];
    const float* g1   = (const float*)d_in[5];
    const float* be1  = (const float*)d_in[6];
    const float* r1w  = (const float*)d_in[7];
    const float* r1b  = (const float*)d_in[8];
    const float* dw2  = (const float*)d_in[9];
    const float* pw2  = (const float*)d_in[10];
    const float* g2   = (const float*)d_in[11];
    const float* be2  = (const float*)d_in[12];
    const float* r2w  = (const float*)d_in[13];
    const float* r2b  = (const float*)d_in[14];
    const float* ll1w = (const float*)d_in[15];
    const float* ll1b = (const float*)d_in[16];
    const float* flw  = (const float*)d_in[17];
    const float* flb  = (const float*)d_in[18];
    float* ws  = (float*)d_ws;
    float* out = (float*)d_out;

    k_moments<<<256, 256, 0, stream>>>(src, dw1, dw2, flw, ws);
    k_prep<<<1, 320, 0, stream>>>(ws, pw1, pw2, g1, be1, g2, be2, r1w, r2w, r1b, r2b);
    k_fused<<<BB, 512, 0, stream>>>(src, dw1, dw2, ll1w, ll1b, flb, ws, out);
}